// Round 1
// baseline (1257.046 us; speedup 1.0000x reference)
//
#include <hip/hip_runtime.h>
#include <math.h>

// 16-qubit statevector sim, 512 batch. State = float2[512][65536] in d_ws (256 MiB).
// Index bit convention: wire w <-> bit (15-w) of the flat index.
// 6 state passes (L-type: 4096 contiguous amps; H-type: 256 hi x 16 lo), then MLP tail.
// Block-0 measurements are dead code in the reference (feats overwritten), so
// RY0 and RX1 fuse per-wire; final RY1+measure replaced by cos*Z - sin*X observable.

#define DIMQ 65536
#define BSZQ 512
#define TILEQ 4096
#define NT 256
#define ACCS 40

struct C2 { float r, i; };
struct G1Q { C2 a, b, c, d; }; // [[a,b],[c,d]]

__device__ __forceinline__ C2 cmul(C2 x, C2 y){ return C2{ x.r*y.r - x.i*y.i, x.r*y.i + x.i*y.r }; }
__device__ __forceinline__ C2 cadd(C2 x, C2 y){ return C2{ x.r + y.r, x.i + y.i }; }
__device__ __forceinline__ G1Q mkRX(float th){
  float cc = cosf(0.5f*th), ss = sinf(0.5f*th);
  return G1Q{ C2{cc,0.f}, C2{0.f,-ss}, C2{0.f,-ss}, C2{cc,0.f} };
}
__device__ __forceinline__ G1Q mkRY(float th){
  float cc = cosf(0.5f*th), ss = sinf(0.5f*th);
  return G1Q{ C2{cc,0.f}, C2{-ss,0.f}, C2{ss,0.f}, C2{cc,0.f} };
}
__device__ __forceinline__ G1Q gmul(G1Q A, G1Q B){ // A*B : B applied first
  return G1Q{ cadd(cmul(A.a,B.a), cmul(A.b,B.c)),
              cadd(cmul(A.a,B.b), cmul(A.b,B.d)),
              cadd(cmul(A.c,B.a), cmul(A.d,B.c)),
              cadd(cmul(A.c,B.b), cmul(A.d,B.d)) };
}

// 1q gate on local bit p of a 4096-amp LDS tile.
// p<6: element-wise dual-read (partner in same wave; wave-lockstep => race-free, LDS conflict-free).
// p>=6: pair-wise (i0 low bits consecutive across lanes => conflict-free).
__device__ __forceinline__ void apply1q(float2* s, int p, G1Q g){
  int tid = threadIdx.x;
  if (p < 6){
    #pragma unroll
    for (int k=0;k<TILEQ/NT;k++){
      int a = k*NT + tid;
      float2 va = s[a];
      float2 vb = s[a ^ (1<<p)];
      bool hi = (a >> p) & 1;
      C2 ca = hi ? g.d : g.a;
      C2 cb = hi ? g.c : g.b;
      float nr = ca.r*va.x - ca.i*va.y + cb.r*vb.x - cb.i*vb.y;
      float ni = ca.r*va.y + ca.i*va.x + cb.r*vb.y + cb.i*vb.x;
      s[a] = make_float2(nr, ni);
    }
  } else {
    #pragma unroll
    for (int k=0;k<TILEQ/2/NT;k++){
      int j = k*NT + tid;
      int low = j & ((1<<p)-1);
      int i0 = ((j >> p) << (p+1)) | low;
      int i1 = i0 | (1 << p);
      float2 a0 = s[i0], a1 = s[i1];
      float nr0 = g.a.r*a0.x - g.a.i*a0.y + g.b.r*a1.x - g.b.i*a1.y;
      float ni0 = g.a.r*a0.y + g.a.i*a0.x + g.b.r*a1.y + g.b.i*a1.x;
      float nr1 = g.c.r*a0.x - g.c.i*a0.y + g.d.r*a1.x - g.d.i*a1.y;
      float ni1 = g.c.r*a0.y + g.c.i*a0.x + g.d.r*a1.y + g.d.i*a1.x;
      s[i0] = make_float2(nr0, ni0);
      s[i1] = make_float2(nr1, ni1);
    }
  }
  __syncthreads();
}

__device__ __forceinline__ void applyCNOT(float2* s, int pc, int pt){
  int tid = threadIdx.x;
  if (pt < 6){
    #pragma unroll
    for (int k=0;k<TILEQ/NT;k++){
      int a = k*NT + tid;
      float2 vb = s[a ^ (1<<pt)];   // unconditional read (reads precede writes in-wave)
      if ((a >> pc) & 1) s[a] = vb;
    }
  } else {
    #pragma unroll
    for (int k=0;k<TILEQ/2/NT;k++){
      int j = k*NT + tid;
      int low = j & ((1<<pt)-1);
      int i0 = ((j >> pt) << (pt+1)) | low;
      int i1 = i0 | (1 << pt);
      if ((i0 >> pc) & 1){
        float2 t0 = s[i0]; s[i0] = s[i1]; s[i1] = t0;
      }
    }
  }
  __syncthreads();
}

// ---- staging ----
// L tile: 4096 contiguous amps. local bits 0..11 = global bits 0..11 (wires 4..15; wire w -> bit 15-w).
__device__ __forceinline__ void loadL(const float2* psi, float2* s, int b, int t){
  const float4* g4 = (const float4*)(psi + (size_t)b*DIMQ + (size_t)t*TILEQ);
  float4* s4 = (float4*)s;
  #pragma unroll
  for (int k=0;k<TILEQ/2/NT;k++){ int f = k*NT + threadIdx.x; s4[f] = g4[f]; }
  __syncthreads();
}
__device__ __forceinline__ void storeL(float2* psi, const float2* s, int b, int t){
  float4* g4 = (float4*)(psi + (size_t)b*DIMQ + (size_t)t*TILEQ);
  const float4* s4 = (const float4*)s;
  #pragma unroll
  for (int k=0;k<TILEQ/2/NT;k++){ int f = k*NT + threadIdx.x; g4[f] = s4[f]; }
}
// H tile: all 256 hi rows x 16 lo cols. local tl = hi*16 + lo4.
// local bits 0..3 = global bits 0..3 (wires 12..15); local bits 4..11 = global bits 8..15 (wire w in 0..7 -> local 11-w).
__device__ __forceinline__ void loadH(const float2* psi, float2* s, int b, int t){
  const float4* g4 = (const float4*)psi;
  float4* s4 = (float4*)s;
  size_t base2 = ((size_t)b*DIMQ + (size_t)t*16) >> 1;
  #pragma unroll
  for (int k=0;k<TILEQ/2/NT;k++){
    int f = k*NT + threadIdx.x;
    int hi = f >> 3, c4 = f & 7;
    s4[f] = g4[base2 + (size_t)hi*128 + c4];
  }
  __syncthreads();
}
__device__ __forceinline__ void storeH(float2* psi, const float2* s, int b, int t){
  float4* g4 = (float4*)psi;
  const float4* s4 = (const float4*)s;
  size_t base2 = ((size_t)b*DIMQ + (size_t)t*16) >> 1;
  #pragma unroll
  for (int k=0;k<TILEQ/2/NT;k++){
    int f = k*NT + threadIdx.x;
    int hi = f >> 3, c4 = f & 7;
    g4[base2 + (size_t)hi*128 + c4] = s4[f];
  }
}

// ---- kernels ----
__global__ __launch_bounds__(NT) void qh_norms(const float* __restrict__ x, float* __restrict__ norms){
  int b = blockIdx.x;
  const float4* xb = (const float4*)(x + (size_t)b*DIMQ);
  float sum = 0.f;
  #pragma unroll 4
  for (int k=0;k<64;k++){
    float4 v = xb[k*NT + threadIdx.x];
    sum += v.x*v.x + v.y*v.y + v.z*v.z + v.w*v.w;
  }
  for (int off=32; off; off>>=1) sum += __shfl_down(sum, off);
  __shared__ float ws[4];
  int lane = threadIdx.x & 63, wv = threadIdx.x >> 6;
  if (lane==0) ws[wv] = sum;
  __syncthreads();
  if (threadIdx.x==0) norms[b] = sqrtf(ws[0]+ws[1]+ws[2]+ws[3]);
}

__global__ __launch_bounds__(NT) void qh_zero(float* __restrict__ p, int n){
  int i = blockIdx.x*NT + threadIdx.x;
  if (i < n) p[i] = 0.f;
}

// P1 (L): normalize input -> complex, random-layer gates on wires 7..15.
__global__ __launch_bounds__(NT) void qh_p1(const float* __restrict__ x, const float* __restrict__ norms,
                                            const float* __restrict__ ra, float2* __restrict__ psi){
  __shared__ __align__(16) float2 s[TILEQ];
  int b = blockIdx.x >> 4, t = blockIdx.x & 15;
  float inv = 1.f / norms[b];
  const float* xb = x + (size_t)b*DIMQ + (size_t)t*TILEQ;
  #pragma unroll
  for (int k=0;k<TILEQ/NT;k++){
    int e = k*NT + threadIdx.x;
    s[e] = make_float2(xb[e]*inv, 0.f);
  }
  __syncthreads();
  applyCNOT(s, 5, 4);            // i=2  CNOT(10->11)
  apply1q(s, 0, mkRX(ra[3]));    // i=3  RX w15
  applyCNOT(s, 6, 5);            // i=5  CNOT(9->10)
  apply1q(s, 1, mkRX(ra[6]));    // i=6  RX w14
  applyCNOT(s, 7, 6);            // i=8  CNOT(8->9)
  apply1q(s, 2, mkRX(ra[9]));    // i=9  RX w13
  applyCNOT(s, 8, 7);            // i=11 CNOT(7->8) (wire7 = bit8, free in L tile)
  apply1q(s, 3, mkRX(ra[12]));   // i=12 RX w12
  apply1q(s, 4, mkRX(ra[15]));   // i=15 RX w11
  apply1q(s, 5, mkRX(ra[18]));   // i=18 RX w10
  apply1q(s, 0, mkRY(ra[19]));   // i=19 RY w15
  storeL(psi, s, b, t);
}

// P2 (H): random-layer hi gates + RX(theta_rx[0]) on wires 0..7 + chain C01..C67.
__global__ __launch_bounds__(NT) void qh_p2(float2* __restrict__ psi, const float* __restrict__ ra,
                                            const float* __restrict__ trx){
  __shared__ __align__(16) float2 s[TILEQ];
  int b = blockIdx.x >> 4, t = blockIdx.x & 15;
  loadH(psi, s, b, t);
  G1Q RX0 = mkRX(trx[0]);
  apply1q(s, 10, gmul(RX0, mkRY(ra[13])));                      // w1: RY(a13) then RX0
  apply1q(s,  9, gmul(RX0, mkRY(ra[10])));                      // w2
  apply1q(s,  8, gmul(RX0, mkRY(ra[7])));                       // w3
  apply1q(s,  7, gmul(RX0, mkRY(ra[4])));                       // w4
  apply1q(s, 11, gmul(RX0, gmul(mkRY(ra[16]), mkRX(ra[0]))));   // w0: RX(a0),RY(a16),RX0
  apply1q(s,  6, mkRY(ra[1]));                                  // w5: RY(a1)
  applyCNOT(s, 5, 4);                                           // i=14 CNOT(6->7)
  applyCNOT(s, 6, 5);                                           // i=17 CNOT(5->6)
  apply1q(s, 6, RX0);                                           // RX0 w5
  apply1q(s, 5, RX0);                                           // RX0 w6
  apply1q(s, 4, RX0);                                           // RX0 w7
  applyCNOT(s, 11, 10); applyCNOT(s, 10, 9); applyCNOT(s, 9, 8);
  applyCNOT(s, 8, 7);   applyCNOT(s, 7, 6);  applyCNOT(s, 6, 5);
  applyCNOT(s, 5, 4);                                           // C01..C67
  storeH(psi, s, b, t);
}

// P3 (L): RX(theta_rx[0]) on wires 8..15 + C78 + C89..C14,15.
__global__ __launch_bounds__(NT) void qh_p3(float2* __restrict__ psi, const float* __restrict__ trx){
  __shared__ __align__(16) float2 s[TILEQ];
  int b = blockIdx.x >> 4, t = blockIdx.x & 15;
  loadL(psi, s, b, t);
  G1Q RX0 = mkRX(trx[0]);
  apply1q(s, 7, RX0); apply1q(s, 6, RX0); apply1q(s, 5, RX0); apply1q(s, 4, RX0);
  apply1q(s, 3, RX0); apply1q(s, 2, RX0); apply1q(s, 1, RX0); apply1q(s, 0, RX0);
  applyCNOT(s, 8, 7);                       // C78 (control wire7 = bit8)
  applyCNOT(s, 7, 6); applyCNOT(s, 6, 5); applyCNOT(s, 5, 4); applyCNOT(s, 4, 3);
  applyCNOT(s, 3, 2); applyCNOT(s, 2, 1); applyCNOT(s, 1, 0);   // C89..C14,15
  storeL(psi, s, b, t);
}

// P4 (H): C15,0 (block0) + fused RX(trx1)*RY(try0) on wires 0..7 + block1 C01..C67.
__global__ __launch_bounds__(NT) void qh_p4(float2* __restrict__ psi, const float* __restrict__ trx,
                                            const float* __restrict__ tryv){
  __shared__ __align__(16) float2 s[TILEQ];
  int b = blockIdx.x >> 4, t = blockIdx.x & 15;
  loadH(psi, s, b, t);
  applyCNOT(s, 0, 11);                      // C15,0: control wire15 (local b0), target wire0 (local b11)
  G1Q U = gmul(mkRX(trx[1]), mkRY(tryv[0]));
  apply1q(s, 11, U); apply1q(s, 10, U); apply1q(s, 9, U); apply1q(s, 8, U);
  apply1q(s,  7, U); apply1q(s,  6, U); apply1q(s, 5, U); apply1q(s, 4, U);
  applyCNOT(s, 11, 10); applyCNOT(s, 10, 9); applyCNOT(s, 9, 8);
  applyCNOT(s, 8, 7);   applyCNOT(s, 7, 6);  applyCNOT(s, 6, 5);
  applyCNOT(s, 5, 4);
  storeH(psi, s, b, t);
}

// P5 (L): fused U on wires 8..15 + C78 + lo chain + partial measurements.
// Accumulates: tot, S_p (p=0..11 free bits; p=12..14 via tile-fixed bits), X on bits 1..7 (wires 14..8).
__global__ __launch_bounds__(NT) void qh_p5(float2* __restrict__ psi, const float* __restrict__ trx,
                                            const float* __restrict__ tryv, float* __restrict__ acc){
  __shared__ __align__(16) float2 s[TILEQ];
  int b = blockIdx.x >> 4, t = blockIdx.x & 15;
  loadL(psi, s, b, t);
  G1Q U = gmul(mkRX(trx[1]), mkRY(tryv[0]));
  apply1q(s, 7, U); apply1q(s, 6, U); apply1q(s, 5, U); apply1q(s, 4, U);
  apply1q(s, 3, U); apply1q(s, 2, U); apply1q(s, 1, U); apply1q(s, 0, U);
  applyCNOT(s, 8, 7);
  applyCNOT(s, 7, 6); applyCNOT(s, 6, 5); applyCNOT(s, 5, 4); applyCNOT(s, 4, 3);
  applyCNOT(s, 3, 2); applyCNOT(s, 2, 1); applyCNOT(s, 1, 0);
  float tot = 0.f, S[12], Xv[7];
  #pragma unroll
  for (int p=0;p<12;p++) S[p] = 0.f;
  #pragma unroll
  for (int q=0;q<7;q++) Xv[q] = 0.f;
  #pragma unroll
  for (int k=0;k<TILEQ/NT;k++){
    int a = k*NT + threadIdx.x;
    float2 va = s[a];
    float a2 = va.x*va.x + va.y*va.y;
    tot += a2;
    #pragma unroll
    for (int p=0;p<12;p++) S[p] += a2 * (float)((a>>p)&1);
    #pragma unroll
    for (int p=1;p<8;p++){              // element-sum == full <X> (each pair counted twice)
      float2 vb = s[a ^ (1<<p)];
      Xv[p-1] += va.x*vb.x + va.y*vb.y;
    }
  }
  float vals[20];
  vals[0] = tot;
  #pragma unroll
  for (int p=0;p<12;p++) vals[1+p] = S[p];
  #pragma unroll
  for (int q=0;q<7;q++) vals[13+q] = Xv[q];
  #pragma unroll
  for (int v=0; v<20; v++){
    float r = vals[v];
    for (int off=32; off; off>>=1) r += __shfl_down(r, off);
    vals[v] = r;
  }
  if ((threadIdx.x & 63) == 0){
    float* A = acc + b*ACCS;
    atomicAdd(A+0, vals[0]);
    #pragma unroll
    for (int p=0;p<12;p++) atomicAdd(A+1+p, vals[1+p]);
    #pragma unroll
    for (int i2=0;i2<3;i2++) if ((t>>i2)&1) atomicAdd(A+13+i2, vals[0]); // fixed bits 12..14
    #pragma unroll
    for (int q=0;q<7;q++) atomicAdd(A+16+q, vals[13+q]);
  }
  storeL(psi, s, b, t);
}

// P6 (H, read-only): apply C15,0 (block1) in-tile, accumulate S_15 (Z_0), X wires 0..7, X wire 15.
__global__ __launch_bounds__(NT) void qh_p6(const float2* __restrict__ psi, float* __restrict__ acc){
  __shared__ __align__(16) float2 s[TILEQ];
  int b = blockIdx.x >> 4, t = blockIdx.x & 15;
  loadH(psi, s, b, t);
  applyCNOT(s, 0, 11);
  float S15 = 0.f, Xv[9];
  #pragma unroll
  for (int w=0;w<9;w++) Xv[w] = 0.f;
  #pragma unroll
  for (int k=0;k<TILEQ/NT;k++){
    int a = k*NT + threadIdx.x;
    float2 va = s[a];
    S15 += (va.x*va.x + va.y*va.y) * (float)((a>>11)&1);
    #pragma unroll
    for (int w=0;w<8;w++){
      float2 vb = s[a ^ (1 << (11-w))];
      Xv[w] += va.x*vb.x + va.y*vb.y;
    }
    float2 vb0 = s[a ^ 1];
    Xv[8] += va.x*vb0.x + va.y*vb0.y;
  }
  float vals[10];
  vals[0] = S15;
  #pragma unroll
  for (int w=0;w<9;w++) vals[1+w] = Xv[w];
  #pragma unroll
  for (int v=0; v<10; v++){
    float r = vals[v];
    for (int off=32; off; off>>=1) r += __shfl_down(r, off);
    vals[v] = r;
  }
  if ((threadIdx.x & 63) == 0){
    float* A = acc + b*ACCS;
    atomicAdd(A+23, vals[0]);
    #pragma unroll
    for (int w=0;w<8;w++) atomicAdd(A+24+w, vals[1+w]);
    atomicAdd(A+32, vals[9]);
  }
}

// Tail: reconstruct Z/X -> M3 (attn), M4 = cos*Z - sin*X (post-RY1 measure), then block-1 MLP head.
__global__ __launch_bounds__(NT) void qh_tail(const float* __restrict__ acc, const float* __restrict__ tryv,
    const float* __restrict__ w1, const float* __restrict__ b1,
    const float* __restrict__ w2, const float* __restrict__ b2,
    const float* __restrict__ g1, const float* __restrict__ be1,
    const float* __restrict__ g2, const float* __restrict__ be2,
    const float* __restrict__ wh, const float* __restrict__ bh,
    float* __restrict__ out){
  int b = blockIdx.x * NT + threadIdx.x;
  if (b >= BSZQ) return;
  const float* A = acc + b*ACCS;
  float tot = A[0];
  float Z[16], X[16];
  #pragma unroll
  for (int w=0; w<16; w++){
    float S = (w == 0) ? A[23] : A[1 + (15 - w)];
    Z[w] = tot - 2.f * S;
  }
  #pragma unroll
  for (int w=0; w<16; w++)
    X[w] = (w <= 7) ? A[24 + w] : ((w == 15) ? A[32] : A[30 - w]);
  float th = tryv[1];
  float ct = cosf(th), st = sinf(th);
  float M4[16];
  #pragma unroll
  for (int w=0; w<16; w++) M4[w] = ct*Z[w] - st*X[w];
  // x = layernorm(M3=Z, g1[1], be1[1])
  float mu = 0.f;
  #pragma unroll
  for (int w=0; w<16; w++) mu += Z[w];
  mu *= (1.f/16.f);
  float var = 0.f;
  #pragma unroll
  for (int w=0; w<16; w++){ float d = Z[w]-mu; var += d*d; }
  var *= (1.f/16.f);
  float rs = rsqrtf(var + 1e-5f);
  float xln[16];
  #pragma unroll
  for (int w=0; w<16; w++) xln[w] = (Z[w]-mu)*rs*g1[16+w] + be1[16+w];
  // h = relu(M4 @ w1[1]^T + b1[1])
  float h[64];
  for (int j=0;j<64;j++){
    float sacc = b1[64 + j];
    #pragma unroll
    for (int w=0; w<16; w++) sacc += M4[w] * w1[1024 + j*16 + w];
    h[j] = fmaxf(sacc, 0.f);
  }
  // ffn = h @ w2[1]^T + b2[1]; y = x + ffn
  float y[16];
  for (int w=0; w<16; w++){
    float sacc = b2[16 + w];
    #pragma unroll
    for (int j=0;j<64;j++) sacc += h[j] * w2[1024 + w*64 + j];
    y[w] = xln[w] + sacc;
  }
  // feats = layernorm(y, g2[1], be2[1]); out = feats @ wh^T + bh
  mu = 0.f;
  #pragma unroll
  for (int w=0; w<16; w++) mu += y[w];
  mu *= (1.f/16.f);
  var = 0.f;
  #pragma unroll
  for (int w=0; w<16; w++){ float d = y[w]-mu; var += d*d; }
  var *= (1.f/16.f);
  rs = rsqrtf(var + 1e-5f);
  float o = bh[0];
  #pragma unroll
  for (int w=0; w<16; w++) o += ((y[w]-mu)*rs*g2[16+w] + be2[16+w]) * wh[w];
  out[b] = o;
}

extern "C" void kernel_launch(void* const* d_in, const int* in_sizes, int n_in,
                              void* d_out, int out_size, void* d_ws, size_t ws_size,
                              hipStream_t stream) {
  const float* states = (const float*)d_in[0];
  const float* ra     = (const float*)d_in[1];
  const float* trx    = (const float*)d_in[2];
  const float* tryv   = (const float*)d_in[3];
  const float* w1     = (const float*)d_in[4];
  const float* b1     = (const float*)d_in[5];
  const float* w2     = (const float*)d_in[6];
  const float* b2     = (const float*)d_in[7];
  const float* g1     = (const float*)d_in[8];
  const float* be1    = (const float*)d_in[9];
  const float* g2     = (const float*)d_in[10];
  const float* be2    = (const float*)d_in[11];
  const float* wh     = (const float*)d_in[12];
  const float* bh     = (const float*)d_in[13];
  float* out = (float*)d_out;

  float2* psi  = (float2*)d_ws;                                   // 256 MiB
  float* norms = (float*)((char*)d_ws + (size_t)BSZQ*DIMQ*sizeof(float2));
  float* acc   = norms + BSZQ;                                    // 512 x 40 floats

  qh_norms<<<BSZQ, NT, 0, stream>>>(states, norms);
  qh_zero<<<(BSZQ*ACCS + NT - 1)/NT, NT, 0, stream>>>(acc, BSZQ*ACCS);
  dim3 g(BSZQ*16);
  qh_p1<<<g, NT, 0, stream>>>(states, norms, ra, psi);
  qh_p2<<<g, NT, 0, stream>>>(psi, ra, trx);
  qh_p3<<<g, NT, 0, stream>>>(psi, trx);
  qh_p4<<<g, NT, 0, stream>>>(psi, trx, tryv);
  qh_p5<<<g, NT, 0, stream>>>(psi, trx, tryv, acc);
  qh_p6<<<g, NT, 0, stream>>>(psi, acc);
  qh_tail<<<2, NT, 0, stream>>>(acc, tryv, w1, b1, w2, b2, g1, be1, g2, be2, wh, bh, out);
}

// Round 2
// 1144.215 us; speedup vs baseline: 1.0986x; 1.0986x over previous
//
#include <hip/hip_runtime.h>
#include <math.h>

// 16-qubit statevector sim, 512 batch. State = float2[512][65536] in d_ws (256 MiB).
// Bit convention: wire w <-> bit (15-w) of the flat index.
// 5 state passes (P5 read-only) + MLP tail. Normalization deferred to tail
// (circuit is unitary: divide all quadratic observables by tot = ||psi||^2).
// P6 eliminated: X_w0..w6 and <X15 X0> measured at end of P4 (U(w15) moved into
// P4 so they commute with the remaining gates); Z_0 via diagonal <Z0 Z15> in P5.
// P5's CNOT chain C78..C(14,15) folded into measurement as linear index
// permutation sigma (y_p = XOR(x_p..x_8), p<=7): Z via bit parities, X via
// masks 3<<(p-1).

#define DIMQ 65536
#define BSZQ 512
#define TILEQ 4096
#define NT 256
#define ACCS 40

struct C2 { float r, i; };
struct G1Q { C2 a, b, c, d; }; // [[a,b],[c,d]]

__device__ __forceinline__ C2 cmul(C2 x, C2 y){ return C2{ x.r*y.r - x.i*y.i, x.r*y.i + x.i*y.r }; }
__device__ __forceinline__ C2 cadd(C2 x, C2 y){ return C2{ x.r + y.r, x.i + y.i }; }
__device__ __forceinline__ G1Q mkRX(float th){
  float cc = cosf(0.5f*th), ss = sinf(0.5f*th);
  return G1Q{ C2{cc,0.f}, C2{0.f,-ss}, C2{0.f,-ss}, C2{cc,0.f} };
}
__device__ __forceinline__ G1Q mkRY(float th){
  float cc = cosf(0.5f*th), ss = sinf(0.5f*th);
  return G1Q{ C2{cc,0.f}, C2{-ss,0.f}, C2{ss,0.f}, C2{cc,0.f} };
}
__device__ __forceinline__ G1Q gmul(G1Q A, G1Q B){ // A*B : B applied first
  return G1Q{ cadd(cmul(A.a,B.a), cmul(A.b,B.c)),
              cadd(cmul(A.a,B.b), cmul(A.b,B.d)),
              cadd(cmul(A.c,B.a), cmul(A.d,B.c)),
              cadd(cmul(A.c,B.b), cmul(A.d,B.d)) };
}

// 1q gate on local bit p of a 4096-amp LDS tile.
__device__ __forceinline__ void apply1q(float2* s, int p, G1Q g){
  int tid = threadIdx.x;
  if (p < 6){
    #pragma unroll
    for (int k=0;k<TILEQ/NT;k++){
      int a = k*NT + tid;
      float2 va = s[a];
      float2 vb = s[a ^ (1<<p)];
      bool hi = (a >> p) & 1;
      C2 ca = hi ? g.d : g.a;
      C2 cb = hi ? g.c : g.b;
      float nr = ca.r*va.x - ca.i*va.y + cb.r*vb.x - cb.i*vb.y;
      float ni = ca.r*va.y + ca.i*va.x + cb.r*vb.y + cb.i*vb.x;
      s[a] = make_float2(nr, ni);
    }
  } else {
    #pragma unroll
    for (int k=0;k<TILEQ/2/NT;k++){
      int j = k*NT + tid;
      int low = j & ((1<<p)-1);
      int i0 = ((j >> p) << (p+1)) | low;
      int i1 = i0 | (1 << p);
      float2 a0 = s[i0], a1 = s[i1];
      float nr0 = g.a.r*a0.x - g.a.i*a0.y + g.b.r*a1.x - g.b.i*a1.y;
      float ni0 = g.a.r*a0.y + g.a.i*a0.x + g.b.r*a1.y + g.b.i*a1.x;
      float nr1 = g.c.r*a0.x - g.c.i*a0.y + g.d.r*a1.x - g.d.i*a1.y;
      float ni1 = g.c.r*a0.y + g.c.i*a0.x + g.d.r*a1.y + g.d.i*a1.x;
      s[i0] = make_float2(nr0, ni0);
      s[i1] = make_float2(nr1, ni1);
    }
  }
  __syncthreads();
}

__device__ __forceinline__ void applyCNOT(float2* s, int pc, int pt){
  int tid = threadIdx.x;
  if (pt < 6){
    #pragma unroll
    for (int k=0;k<TILEQ/NT;k++){
      int a = k*NT + tid;
      float2 vb = s[a ^ (1<<pt)];
      if ((a >> pc) & 1) s[a] = vb;
    }
  } else {
    #pragma unroll
    for (int k=0;k<TILEQ/2/NT;k++){
      int j = k*NT + tid;
      int low = j & ((1<<pt)-1);
      int i0 = ((j >> pt) << (pt+1)) | low;
      int i1 = i0 | (1 << pt);
      if ((i0 >> pc) & 1){
        float2 t0 = s[i0]; s[i0] = s[i1]; s[i1] = t0;
      }
    }
  }
  __syncthreads();
}

// ---- staging ----
__device__ __forceinline__ void loadL(const float2* psi, float2* s, int b, int t){
  const float4* g4 = (const float4*)(psi + (size_t)b*DIMQ + (size_t)t*TILEQ);
  float4* s4 = (float4*)s;
  #pragma unroll
  for (int k=0;k<TILEQ/2/NT;k++){ int f = k*NT + threadIdx.x; s4[f] = g4[f]; }
  __syncthreads();
}
__device__ __forceinline__ void storeL(float2* psi, const float2* s, int b, int t){
  float4* g4 = (float4*)(psi + (size_t)b*DIMQ + (size_t)t*TILEQ);
  const float4* s4 = (const float4*)s;
  #pragma unroll
  for (int k=0;k<TILEQ/2/NT;k++){ int f = k*NT + threadIdx.x; g4[f] = s4[f]; }
}
// H tile: local bits 0..3 = global 0..3; local 4..11 = global 8..15.
__device__ __forceinline__ void loadH(const float2* psi, float2* s, int b, int t){
  const float4* g4 = (const float4*)psi;
  float4* s4 = (float4*)s;
  size_t base2 = ((size_t)b*DIMQ + (size_t)t*16) >> 1;
  #pragma unroll
  for (int k=0;k<TILEQ/2/NT;k++){
    int f = k*NT + threadIdx.x;
    int hi = f >> 3, c4 = f & 7;
    s4[f] = g4[base2 + (size_t)hi*128 + c4];
  }
  __syncthreads();
}
__device__ __forceinline__ void storeH(float2* psi, const float2* s, int b, int t){
  float4* g4 = (float4*)psi;
  const float4* s4 = (const float4*)s;
  size_t base2 = ((size_t)b*DIMQ + (size_t)t*16) >> 1;
  #pragma unroll
  for (int k=0;k<TILEQ/2/NT;k++){
    int f = k*NT + threadIdx.x;
    int hi = f >> 3, c4 = f & 7;
    g4[base2 + (size_t)hi*128 + c4] = s4[f];
  }
}

// ---- kernels ----

// P1 (L): raw f32 input -> complex, random-layer gates on wires 7..15.
// t==0 blocks also zero the accumulator (consumed by P4/P5 atomics, later kernels).
__global__ __launch_bounds__(NT) void qh_p1(const float* __restrict__ x,
                                            const float* __restrict__ ra,
                                            float2* __restrict__ psi,
                                            float* __restrict__ acc){
  __shared__ __align__(16) float2 s[TILEQ];
  int b = blockIdx.x >> 4, t = blockIdx.x & 15;
  if (t == 0 && threadIdx.x < ACCS) acc[b*ACCS + threadIdx.x] = 0.f;
  const float* xb = x + (size_t)b*DIMQ + (size_t)t*TILEQ;
  #pragma unroll
  for (int k=0;k<TILEQ/NT;k++){
    int e = k*NT + threadIdx.x;
    s[e] = make_float2(xb[e], 0.f);
  }
  __syncthreads();
  applyCNOT(s, 5, 4);            // i=2  CNOT(10->11)
  apply1q(s, 0, mkRX(ra[3]));    // i=3  RX w15
  applyCNOT(s, 6, 5);            // i=5  CNOT(9->10)
  apply1q(s, 1, mkRX(ra[6]));    // i=6  RX w14
  applyCNOT(s, 7, 6);            // i=8  CNOT(8->9)
  apply1q(s, 2, mkRX(ra[9]));    // i=9  RX w13
  applyCNOT(s, 8, 7);            // i=11 CNOT(7->8)
  apply1q(s, 3, mkRX(ra[12]));   // i=12 RX w12
  apply1q(s, 4, mkRX(ra[15]));   // i=15 RX w11
  apply1q(s, 5, mkRX(ra[18]));   // i=18 RX w10
  apply1q(s, 0, mkRY(ra[19]));   // i=19 RY w15
  storeL(psi, s, b, t);
}

// P2 (H): random-layer low gates + RX(theta_rx[0]) on wires 0..7 + chain C01..C67.
__global__ __launch_bounds__(NT) void qh_p2(float2* __restrict__ psi, const float* __restrict__ ra,
                                            const float* __restrict__ trx){
  __shared__ __align__(16) float2 s[TILEQ];
  int b = blockIdx.x >> 4, t = blockIdx.x & 15;
  loadH(psi, s, b, t);
  G1Q RX0 = mkRX(trx[0]);
  apply1q(s, 10, gmul(RX0, mkRY(ra[13])));                      // w1
  apply1q(s,  9, gmul(RX0, mkRY(ra[10])));                      // w2
  apply1q(s,  8, gmul(RX0, mkRY(ra[7])));                       // w3
  apply1q(s,  7, gmul(RX0, mkRY(ra[4])));                       // w4
  apply1q(s, 11, gmul(RX0, gmul(mkRY(ra[16]), mkRX(ra[0]))));   // w0
  apply1q(s,  6, mkRY(ra[1]));                                  // w5
  applyCNOT(s, 5, 4);                                           // i=14 CNOT(6->7)
  applyCNOT(s, 6, 5);                                           // i=17 CNOT(5->6)
  apply1q(s, 6, RX0);                                           // RX0 w5
  apply1q(s, 5, RX0);                                           // RX0 w6
  apply1q(s, 4, RX0);                                           // RX0 w7
  applyCNOT(s, 11, 10); applyCNOT(s, 10, 9); applyCNOT(s, 9, 8);
  applyCNOT(s, 8, 7);   applyCNOT(s, 7, 6);  applyCNOT(s, 6, 5);
  applyCNOT(s, 5, 4);                                           // C01..C67 (block0)
  storeH(psi, s, b, t);
}

// P3 (L): RX(theta_rx[0]) on wires 8..15 + C78 + C89..C(14,15) (block0).
__global__ __launch_bounds__(NT) void qh_p3(float2* __restrict__ psi, const float* __restrict__ trx){
  __shared__ __align__(16) float2 s[TILEQ];
  int b = blockIdx.x >> 4, t = blockIdx.x & 15;
  loadL(psi, s, b, t);
  G1Q RX0 = mkRX(trx[0]);
  apply1q(s, 7, RX0); apply1q(s, 6, RX0); apply1q(s, 5, RX0); apply1q(s, 4, RX0);
  apply1q(s, 3, RX0); apply1q(s, 2, RX0); apply1q(s, 1, RX0); apply1q(s, 0, RX0);
  applyCNOT(s, 8, 7);
  applyCNOT(s, 7, 6); applyCNOT(s, 6, 5); applyCNOT(s, 5, 4); applyCNOT(s, 4, 3);
  applyCNOT(s, 3, 2); applyCNOT(s, 2, 1); applyCNOT(s, 1, 0);
  storeL(psi, s, b, t);
}

// P4 (H): C(15,0) block0 + U = RX(trx1)*RY(try0) on w0..w7 AND w15 + block1 C01..C67,
// then measure X_w0..w6 and <X15 X0> (these commute with all remaining gates).
__global__ __launch_bounds__(NT) void qh_p4(float2* __restrict__ psi, const float* __restrict__ trx,
                                            const float* __restrict__ tryv, float* __restrict__ acc){
  __shared__ __align__(16) float2 s[TILEQ];
  int b = blockIdx.x >> 4, t = blockIdx.x & 15;
  loadH(psi, s, b, t);
  applyCNOT(s, 0, 11);                      // C(15->0) block0 (ctrl w15=local0, tgt w0=local11)
  G1Q U = gmul(mkRX(trx[1]), mkRY(tryv[0]));
  apply1q(s, 11, U); apply1q(s, 10, U); apply1q(s, 9, U); apply1q(s, 8, U);
  apply1q(s,  7, U); apply1q(s,  6, U); apply1q(s, 5, U); apply1q(s, 4, U);
  apply1q(s,  0, U);                        // U on w15 (moved here from P5)
  applyCNOT(s, 11, 10); applyCNOT(s, 10, 9); applyCNOT(s, 9, 8);
  applyCNOT(s, 8, 7);   applyCNOT(s, 7, 6);  applyCNOT(s, 6, 5);
  applyCNOT(s, 5, 4);                       // block1 C01..C67
  // measure X_w0..w6 (local bits 11..5) and X15*X0 (mask 0x801)
  const int mloc[8] = {2048, 1024, 512, 256, 128, 64, 32, 0x801};
  float Xv[8];
  #pragma unroll
  for (int j=0;j<8;j++) Xv[j] = 0.f;
  int tid = threadIdx.x;
  #pragma unroll
  for (int k=0;k<TILEQ/NT;k++){
    int a = k*NT + tid;
    float2 va = s[a];
    #pragma unroll
    for (int j=0;j<8;j++){
      float2 vb = s[a ^ mloc[j]];
      Xv[j] += va.x*vb.x + va.y*vb.y;
    }
  }
  #pragma unroll
  for (int j=0;j<8;j++){
    float r = Xv[j];
    for (int off=32; off; off>>=1) r += __shfl_down(r, off);
    Xv[j] = r;
  }
  if ((tid & 63) == 0){
    float* A = acc + b*ACCS;
    #pragma unroll
    for (int j=0;j<7;j++) atomicAdd(A+25+j, Xv[j]);   // X_w0..w6
    atomicAdd(A+32, Xv[7]);                           // <X15 X0>
  }
  storeH(psi, s, b, t);
}

// P5 (L, read-only): U on w8..w14 (bits 7..1), then measure with the chain
// C78..C(14,15) folded in as index permutation sigma: y_p = XOR(x_p..x_8) (p<=7).
// Element a = k*256 + tid: bits 0..7 = tid (fixed/thread), bits 8..11 = k (compile-time).
__global__ __launch_bounds__(NT) void qh_p5(const float2* __restrict__ psi, const float* __restrict__ trx,
                                            const float* __restrict__ tryv, float* __restrict__ acc){
  __shared__ __align__(16) float2 s[TILEQ];
  int b = blockIdx.x >> 4, t = blockIdx.x & 15;
  loadL(psi, s, b, t);
  G1Q U = gmul(mkRX(trx[1]), mkRY(tryv[0]));
  apply1q(s, 7, U); apply1q(s, 6, U); apply1q(s, 5, U); apply1q(s, 4, U);
  apply1q(s, 3, U); apply1q(s, 2, U); apply1q(s, 1, U);   // w8..w14
  int tid = threadIdx.x;
  float E0=0.f, E1=0.f, K9=0.f, K10=0.f, K11=0.f, Xv[8];
  #pragma unroll
  for (int j=0;j<8;j++) Xv[j] = 0.f;
  #pragma unroll
  for (int k=0;k<TILEQ/NT;k++){
    int a = k*NT + tid;
    float2 va = s[a];
    float a2 = va.x*va.x + va.y*va.y;
    if (k & 1) E1 += a2; else E0 += a2;   // x_8 = k bit0
    if (k & 2) K9  += a2;                 // x_9
    if (k & 4) K10 += a2;                 // x_10
    if (k & 8) K11 += a2;                 // x_11
    #pragma unroll
    for (int p=1;p<9;p++){                // X on post-bits 1..8: masks 3<<(p-1)
      float2 vb = s[a ^ (3<<(p-1))];
      Xv[p-1] += va.x*vb.x + va.y*vb.y;
    }
  }
  // per-thread parities of tid bits p..7 -> select E0/E1 for S_p (p<=7)
  int P[8];
  P[7] = (tid >> 7) & 1;
  #pragma unroll
  for (int p=6;p>=0;p--) P[p] = P[p+1] ^ ((tid >> p) & 1);
  float vals[21];
  vals[0] = E0 + E1;                      // tot
  #pragma unroll
  for (int p=0;p<8;p++) vals[1+p] = P[p] ? E0 : E1;   // S_0..S_7 (post-sigma)
  vals[9]  = E1;                          // S_8
  vals[10] = K9; vals[11] = K10; vals[12] = K11;      // S_9..S_11
  #pragma unroll
  for (int j=0;j<8;j++) vals[13+j] = Xv[j];
  #pragma unroll
  for (int v=0; v<21; v++){
    float r = vals[v];
    for (int off=32; off; off>>=1) r += __shfl_down(r, off);
    vals[v] = r;
  }
  if ((tid & 63) == 0){
    float* A = acc + b*ACCS;
    atomicAdd(A+0, vals[0]);
    #pragma unroll
    for (int p=0;p<12;p++) atomicAdd(A+1+p, vals[1+p]);
    #pragma unroll
    for (int i2=0;i2<3;i2++) if ((t>>i2)&1) atomicAdd(A+13+i2, vals[0]);  // bits 12..14
    float zz = vals[0] - 2.f*vals[1];     // <Z(bit0-post)> partial, signed by bit15
    if (t & 8) zz = -zz;
    atomicAdd(A+16, zz);                  // <Z0 Z15> -> final Z_w0
    #pragma unroll
    for (int j=0;j<8;j++) atomicAdd(A+17+j, vals[13+j]);  // X post-bits 1..8 = X_w14..w7
  }
}

// Tail: Z/X from acc (divide by tot), M4 = cos*Z - sin*X, block-1 MLP head.
__global__ __launch_bounds__(NT) void qh_tail(const float* __restrict__ acc, const float* __restrict__ tryv,
    const float* __restrict__ w1, const float* __restrict__ b1,
    const float* __restrict__ w2, const float* __restrict__ b2,
    const float* __restrict__ g1, const float* __restrict__ be1,
    const float* __restrict__ g2, const float* __restrict__ be2,
    const float* __restrict__ wh, const float* __restrict__ bh,
    float* __restrict__ out){
  int b = blockIdx.x * NT + threadIdx.x;
  if (b >= BSZQ) return;
  const float* A = acc + b*ACCS;
  float tot = A[0];
  float inv = 1.f / tot;
  float Z[16], X[16];
  Z[0] = A[16] * inv;                       // <Z0 Z15> trick
  Z[1] = 1.f - 2.f*A[15]*inv;               // bit14
  Z[2] = 1.f - 2.f*A[14]*inv;               // bit13
  Z[3] = 1.f - 2.f*A[13]*inv;               // bit12
  #pragma unroll
  for (int w=4; w<15; w++) Z[w] = 1.f - 2.f*A[1 + (15-w)]*inv;   // bits 11..1
  Z[15] = 1.f - 2.f*A[1]*inv;               // bit0 (post-sigma S_0)
  #pragma unroll
  for (int w=0; w<7; w++) X[w] = A[25+w]*inv;
  #pragma unroll
  for (int w=7; w<15; w++) X[w] = A[16 + (15-w)]*inv;  // acc[17+(p-1)], p=15-w
  X[15] = A[32]*inv;
  float th = tryv[1];
  float ct = cosf(th), st = sinf(th);
  float M4[16];
  #pragma unroll
  for (int w=0; w<16; w++) M4[w] = ct*Z[w] - st*X[w];
  // x = layernorm(Z, g1[1], be1[1])
  float mu = 0.f;
  #pragma unroll
  for (int w=0; w<16; w++) mu += Z[w];
  mu *= (1.f/16.f);
  float var = 0.f;
  #pragma unroll
  for (int w=0; w<16; w++){ float d = Z[w]-mu; var += d*d; }
  var *= (1.f/16.f);
  float rs = rsqrtf(var + 1e-5f);
  float xln[16];
  #pragma unroll
  for (int w=0; w<16; w++) xln[w] = (Z[w]-mu)*rs*g1[16+w] + be1[16+w];
  // h = relu(M4 @ w1[1]^T + b1[1])
  float h[64];
  for (int j=0;j<64;j++){
    float sacc = b1[64 + j];
    #pragma unroll
    for (int w=0; w<16; w++) sacc += M4[w] * w1[1024 + j*16 + w];
    h[j] = fmaxf(sacc, 0.f);
  }
  // ffn = h @ w2[1]^T + b2[1]; y = x + ffn
  float y[16];
  for (int w=0; w<16; w++){
    float sacc = b2[16 + w];
    #pragma unroll
    for (int j=0;j<64;j++) sacc += h[j] * w2[1024 + w*64 + j];
    y[w] = xln[w] + sacc;
  }
  // feats = layernorm(y, g2[1], be2[1]); out = feats @ wh^T + bh
  mu = 0.f;
  #pragma unroll
  for (int w=0; w<16; w++) mu += y[w];
  mu *= (1.f/16.f);
  var = 0.f;
  #pragma unroll
  for (int w=0; w<16; w++){ float d = y[w]-mu; var += d*d; }
  var *= (1.f/16.f);
  rs = rsqrtf(var + 1e-5f);
  float o = bh[0];
  #pragma unroll
  for (int w=0; w<16; w++) o += ((y[w]-mu)*rs*g2[16+w] + be2[16+w]) * wh[w];
  out[b] = o;
}

extern "C" void kernel_launch(void* const* d_in, const int* in_sizes, int n_in,
                              void* d_out, int out_size, void* d_ws, size_t ws_size,
                              hipStream_t stream) {
  const float* states = (const float*)d_in[0];
  const float* ra     = (const float*)d_in[1];
  const float* trx    = (const float*)d_in[2];
  const float* tryv   = (const float*)d_in[3];
  const float* w1     = (const float*)d_in[4];
  const float* b1     = (const float*)d_in[5];
  const float* w2     = (const float*)d_in[6];
  const float* b2     = (const float*)d_in[7];
  const float* g1     = (const float*)d_in[8];
  const float* be1    = (const float*)d_in[9];
  const float* g2     = (const float*)d_in[10];
  const float* be2    = (const float*)d_in[11];
  const float* wh     = (const float*)d_in[12];
  const float* bh     = (const float*)d_in[13];
  float* out = (float*)d_out;

  float2* psi = (float2*)d_ws;                                   // 256 MiB
  float* acc  = (float*)((char*)d_ws + (size_t)BSZQ*DIMQ*sizeof(float2)); // 512 x 40

  dim3 g(BSZQ*16);
  qh_p1<<<g, NT, 0, stream>>>(states, ra, psi, acc);
  qh_p2<<<g, NT, 0, stream>>>(psi, ra, trx);
  qh_p3<<<g, NT, 0, stream>>>(psi, trx);
  qh_p4<<<g, NT, 0, stream>>>(psi, trx, tryv, acc);
  qh_p5<<<g, NT, 0, stream>>>(psi, trx, tryv, acc);
  qh_tail<<<2, NT, 0, stream>>>(acc, tryv, w1, b1, w2, b2, g1, be1, g2, be2, wh, bh, out);
}

// Round 3
// 873.956 us; speedup vs baseline: 1.4383x; 1.3092x over previous
//
#include <hip/hip_runtime.h>
#include <math.h>

// 16-qubit statevector, 512 batch, float2[512][65536] in d_ws (256 MiB).
// Bit convention: wire w <-> bit (15-w). 4 state passes + tail.
// Register-resident engine: 128 thr/block, 32 amps/thread (5 reg bits),
// gates = unrolled VGPR math; LDS only for layout transposes (XOR-swizzled).
// chain0 = linear perm T (x_p -> xor(x_p..x_15)); folded into P4 load/store
// and P5 load as addr = idx ^ (idx>>1) (= T^-1). C(w15->w0) of chain0 and
// chain1's head/tail are register CNOTs in P4; chain1's low part + C(w15->w0)
// folded into P5's measurement (round-2 scheme, verified).

#define NT 128
#define ACCS 40
#define BSZQ 512

struct C2 { float r, i; };
struct G1Q { C2 a, b, c, d; };

__device__ __forceinline__ C2 cmul(C2 x, C2 y){ return C2{ x.r*y.r - x.i*y.i, x.r*y.i + x.i*y.r }; }
__device__ __forceinline__ C2 cadd(C2 x, C2 y){ return C2{ x.r + y.r, x.i + y.i }; }
__device__ __forceinline__ G1Q mkRX(float th){
  float cc = cosf(0.5f*th), ss = sinf(0.5f*th);
  return G1Q{ C2{cc,0.f}, C2{0.f,-ss}, C2{0.f,-ss}, C2{cc,0.f} };
}
__device__ __forceinline__ G1Q mkRY(float th){
  float cc = cosf(0.5f*th), ss = sinf(0.5f*th);
  return G1Q{ C2{cc,0.f}, C2{-ss,0.f}, C2{ss,0.f}, C2{cc,0.f} };
}
__device__ __forceinline__ G1Q gmul(G1Q A, G1Q B){ // A*B, B applied first
  return G1Q{ cadd(cmul(A.a,B.a), cmul(A.b,B.c)),
              cadd(cmul(A.a,B.b), cmul(A.b,B.d)),
              cadd(cmul(A.c,B.a), cmul(A.d,B.c)),
              cadd(cmul(A.c,B.b), cmul(A.d,B.d)) };
}

__device__ __forceinline__ int swz(int i){ return i ^ ((i>>5)&31); }

// 1q gate on register-bit q of v[32]
__device__ __forceinline__ void greg(float2* v, const G1Q g, const int q){
  const int bq = 1<<q;
  #pragma unroll
  for (int r=0;r<32;r++){
    if (r & bq) continue;
    float2 a0 = v[r], a1 = v[r|bq];
    v[r].x    = g.a.r*a0.x - g.a.i*a0.y + g.b.r*a1.x - g.b.i*a1.y;
    v[r].y    = g.a.r*a0.y + g.a.i*a0.x + g.b.r*a1.y + g.b.i*a1.x;
    v[r|bq].x = g.c.r*a0.x - g.c.i*a0.y + g.d.r*a1.x - g.d.i*a1.y;
    v[r|bq].y = g.c.r*a0.y + g.c.i*a0.x + g.d.r*a1.y + g.d.i*a1.x;
  }
}
// CNOT (ctrl reg-bit qc, tgt reg-bit qt): pure register permutation
__device__ __forceinline__ void creg(float2* v, const int qc, const int qt){
  #pragma unroll
  for (int r=0;r<32;r++){
    if ((r & (1<<qc)) && !(r & (1<<qt))){
      float2 tmp = v[r]; v[r] = v[r|(1<<qt)]; v[r|(1<<qt)] = tmp;
    }
  }
}
// sum_r Re(v[r] * conj(v[r^m])) over all 32 regs (pairs counted twice = <X>)
__device__ __forceinline__ float xdot(const float2* v, const int m){
  float s = 0.f;
  #pragma unroll
  for (int r=0;r<32;r++) s += v[r].x*v[r^m].x + v[r].y*v[r^m].y;
  return s;
}

// P1 (L-tile): input -> complex; random gates bits 0..8 + RY(a19) + RX0 on g0..7.
__global__ __launch_bounds__(NT) void qr_p1(const float* __restrict__ x, const float* __restrict__ ra,
                                            const float* __restrict__ trx, float2* __restrict__ psi,
                                            float* __restrict__ acc){
  __shared__ float2 s[4096];
  int b = blockIdx.x >> 4, t = blockIdx.x & 15;
  int tid = threadIdx.x;
  if (t == 0 && tid < ACCS) acc[b*ACCS + tid] = 0.f;
  float trx0 = trx[0];
  G1Q RX0 = mkRX(trx0);
  float2 v[32];
  // phase alpha: regs g0..g4 (32 consecutive elems/thread)
  const float4* xb = (const float4*)(x + (size_t)b*65536 + t*4096 + tid*32);
  #pragma unroll
  for (int j=0;j<8;j++){
    float4 q = xb[j];
    v[4*j+0] = make_float2(q.x, 0.f);
    v[4*j+1] = make_float2(q.y, 0.f);
    v[4*j+2] = make_float2(q.z, 0.f);
    v[4*j+3] = make_float2(q.w, 0.f);
  }
  greg(v, gmul(RX0, gmul(mkRY(ra[19]), mkRX(ra[3]))), 0);  // g0: RX(a3),RY(a19),RX0
  greg(v, mkRX(trx0 + ra[6]),  1);                         // g1
  greg(v, mkRX(trx0 + ra[9]),  2);                         // g2
  greg(v, mkRX(trx0 + ra[12]), 3);                         // g3
  greg(v, mkRX(trx0 + ra[15]), 4);                         // g4 (commutes w/ CNOT tgt)
  #pragma unroll
  for (int j=0;j<32;j++) s[swz(tid*32 + j)] = v[j];
  __syncthreads();
  // phase beta: regs g4..g8
  #pragma unroll
  for (int r=0;r<32;r++) v[r] = s[swz((tid&15) | (r<<4) | ((tid>>4)<<9))];
  creg(v, 1, 0);                       // C(w10->w11)
  creg(v, 2, 1);                       // C(w9->w10)
  creg(v, 3, 2);                       // C(w8->w9)
  creg(v, 4, 3);                       // C(w7->w8)
  greg(v, mkRX(trx0 + ra[18]), 1);     // g5
  greg(v, RX0, 2);                     // g6
  greg(v, RX0, 3);                     // g7
  float2* pb = psi + (size_t)b*65536 + t*4096;
  #pragma unroll
  for (int r=0;r<32;r++) pb[(tid&15) | (r<<4) | ((tid>>4)<<9)] = v[r];
}

// P2 (H-tile): random gates wires 0..7 + RX0 wires 0..7. Store standard.
__global__ __launch_bounds__(NT) void qr_p2(float2* __restrict__ psi, const float* __restrict__ ra,
                                            const float* __restrict__ trx){
  __shared__ float2 s[4096];
  int b = blockIdx.x >> 4, t = blockIdx.x & 15;
  int tid = threadIdx.x;
  float trx0 = trx[0];
  G1Q RX0 = mkRX(trx0);
  float2 v[32];
  // phase A: regs l4..l8 (g8..g12)
  float2* base = psi + (size_t)b*65536 + ((size_t)((tid>>4)<<5)<<8) + (t<<4) + (tid&15);
  #pragma unroll
  for (int r=0;r<32;r++) v[r] = base[r<<8];
  greg(v, gmul(RX0, mkRY(ra[4])), 3);   // w4 (l7)
  greg(v, mkRY(ra[1]), 2);              // w5 RY(a1) (l6)
  creg(v, 1, 0);                        // C(w6->w7)
  creg(v, 2, 1);                        // C(w5->w6)
  greg(v, RX0, 2);                      // w5
  greg(v, RX0, 1);                      // w6
  greg(v, RX0, 0);                      // w7
  greg(v, gmul(RX0, mkRY(ra[7])), 4);   // w3 (l8)
  #pragma unroll
  for (int r=0;r<32;r++) s[swz((tid&15) | (r<<4) | ((tid>>4)<<9))] = v[r];
  __syncthreads();
  // phase B: regs l7..l11 (g11..g15)
  #pragma unroll
  for (int r=0;r<32;r++) v[r] = s[swz((tid&15) | (((tid>>4)&7)<<4) | (r<<7))];
  greg(v, gmul(RX0, mkRY(ra[10])), 2);  // w2 (l9)
  greg(v, gmul(RX0, mkRY(ra[13])), 3);  // w1 (l10)
  greg(v, gmul(RX0, gmul(mkRY(ra[16]), mkRX(ra[0]))), 4); // w0 (l11)
  float2* sb = psi + (size_t)b*65536 + (((size_t)(tid>>4)&7)<<8) + (t<<4) + (tid&15);
  #pragma unroll
  for (int r=0;r<32;r++) sb[r<<11] = v[r];
}

// P4 (H-tile, T folded into load+store addr): K + U on 12 wires + chain1
// C01..C67 + X measures (w0..w6, w15-pair).
__global__ __launch_bounds__(NT) void qr_p4(float2* __restrict__ psi, const float* __restrict__ trx,
                                            const float* __restrict__ tryv, float* __restrict__ acc){
  __shared__ float2 s[4096];
  int b = blockIdx.x >> 4, t = blockIdx.x & 15;
  int tid = threadIdx.x;
  G1Q U = gmul(mkRX(trx[1]), mkRY(tryv[0]));
  float2 v[32];
  float2* pb = psi + (size_t)b*65536;
  // A5: regs l0..l4; load with T^-1 gather (addr = yg ^ (yg>>1))
  #pragma unroll
  for (int j=0;j<32;j++){
    int yl = tid*32 + j;
    int yg = (yl & 15) | (t<<4) | ((yl>>4)<<8);
    v[j] = pb[yg ^ (yg>>1)];
  }
  greg(v, U, 1); greg(v, U, 2); greg(v, U, 3);  // g1,g2,g3 (w14,w13,w12)
  greg(v, U, 4);                                // l4 = g8 (w7)
  #pragma unroll
  for (int j=0;j<32;j++) s[swz(tid*32 + j)] = v[j];
  __syncthreads();
  // C5: regs {l8,l9,l10,l11,l0} (r0..r3 -> l8..l11, r4 -> l0)
  #pragma unroll
  for (int r=0;r<32;r++)
    v[r] = s[swz((r>>4) | ((tid&7)<<1) | (((tid>>3)&15)<<4) | ((r&15)<<8))];
  creg(v, 4, 3);        // K: C(w15->w0) (chain0 tail)
  greg(v, U, 4);        // l0  (w15)
  greg(v, U, 0);        // l8  (w3)
  greg(v, U, 1);        // l9  (w2)
  greg(v, U, 2);        // l10 (w1)
  greg(v, U, 3);        // l11 (w0)
  creg(v, 3, 2);        // chain1 C(w0->w1)
  creg(v, 2, 1);        // C(w1->w2)
  creg(v, 1, 0);        // C(w2->w3)
  float Xa = xdot(v, 8);   // e_l11 = X_w0
  float Xb = xdot(v, 4);   // e_l10 = X_w1
  float Xc = xdot(v, 2);   // e_l9  = X_w2
  float Xd = xdot(v, 24);  // e_l11 ^ e_l0 = <X_w0 X_w15>
  __syncthreads();
  #pragma unroll
  for (int r=0;r<32;r++)
    s[swz((r>>4) | ((tid&7)<<1) | (((tid>>3)&15)<<4) | ((r&15)<<8))] = v[r];
  __syncthreads();
  // B5: regs l4..l8
  #pragma unroll
  for (int r=0;r<32;r++) v[r] = s[swz((tid&15) | (r<<4) | ((tid>>4)<<9))];
  greg(v, U, 1);        // l5 (w6)
  greg(v, U, 2);        // l6 (w5)
  greg(v, U, 3);        // l7 (w4)
  creg(v, 4, 3);        // C(w3->w4)
  creg(v, 3, 2);        // C(w4->w5)
  creg(v, 2, 1);        // C(w5->w6)
  creg(v, 1, 0);        // C(w6->w7)
  float Xe = xdot(v, 16);  // e_l8 = X_w3
  float Xf = xdot(v, 8);   // e_l7 = X_w4
  float Xg = xdot(v, 4);   // e_l6 = X_w5
  float Xh = xdot(v, 2);   // e_l5 = X_w6
  // store with same T^-1 addresses (memory stays psi4 ∘ T; P5 un-folds)
  #pragma unroll
  for (int r=0;r<32;r++){
    int yl = (tid&15) | (r<<4) | ((tid>>4)<<9);
    int yg = (yl & 15) | (t<<4) | ((yl>>4)<<8);
    pb[yg ^ (yg>>1)] = v[r];
  }
  float vals[8] = {Xa, Xb, Xc, Xe, Xf, Xg, Xh, Xd};
  #pragma unroll
  for (int i=0;i<8;i++){
    float rr = vals[i];
    for (int off=32; off; off>>=1) rr += __shfl_down(rr, off);
    vals[i] = rr;
  }
  if ((tid & 63) == 0){
    float* A = acc + b*ACCS;
    #pragma unroll
    for (int i=0;i<7;i++) atomicAdd(A+25+i, vals[i]);
    atomicAdd(A+32, vals[7]);
  }
}

// P5 (L-tile, read-only, T un-fold gather): U on g4..7, all Z + X w7..w14.
__global__ __launch_bounds__(NT) void qr_p5(const float2* __restrict__ psi, const float* __restrict__ trx,
                                            const float* __restrict__ tryv, float* __restrict__ acc){
  __shared__ float2 s[4096];
  int b = blockIdx.x >> 4, t = blockIdx.x & 15;
  int tid = threadIdx.x;
  G1Q U = gmul(mkRX(trx[1]), mkRY(tryv[0]));
  float2 v[32];
  const float2* pb = psi + (size_t)b*65536;
  // layout A: regs g4..g8
  #pragma unroll
  for (int r=0;r<32;r++){
    int ul = (tid&15) | (r<<4) | ((tid>>4)<<9);
    int ug = (t<<12) | ul;
    v[r] = pb[ug ^ (ug>>1)];
  }
  greg(v, U, 0); greg(v, U, 1); greg(v, U, 2); greg(v, U, 3);  // g4..g7
  float tot=0.f, S4=0.f, S5=0.f, S6=0.f, S7=0.f, S8=0.f;
  #pragma unroll
  for (int r=0;r<32;r++){
    float a2 = v[r].x*v[r].x + v[r].y*v[r].y;
    tot += a2;
    if (__popc(r)&1)    S4 += a2;
    if (__popc(r>>1)&1) S5 += a2;
    if (__popc(r>>2)&1) S6 += a2;
    if (__popc(r>>3)&1) S7 += a2;
    if (r & 16)         S8 += a2;
  }
  float X45 = xdot(v,3), X56 = xdot(v,6), X67 = xdot(v,12), X78 = xdot(v,24);
  #pragma unroll
  for (int r=0;r<32;r++) s[swz((tid&15) | (r<<4) | ((tid>>4)<<9))] = v[r];
  __syncthreads();
  // layout B: regs g0..g4
  #pragma unroll
  for (int r=0;r<32;r++) v[r] = s[swz(r | (tid<<5))];
  float totB=0.f, Q0=0.f, Q1=0.f, Q2=0.f, Q3=0.f;
  #pragma unroll
  for (int r=0;r<32;r++){
    float a2 = v[r].x*v[r].x + v[r].y*v[r].y;
    totB += a2;
    if (__popc(r)&1)    Q0 += a2;
    if (__popc(r>>1)&1) Q1 += a2;
    if (__popc(r>>2)&1) Q2 += a2;
    if (__popc(r>>3)&1) Q3 += a2;
  }
  float X01 = xdot(v,3), X12 = xdot(v,6), X23 = xdot(v,12), X34 = xdot(v,24);
  int tp = __popc(tid & 15) & 1;
  float S0 = tp ? totB - Q0 : Q0;
  float S1 = tp ? totB - Q1 : Q1;
  float S2 = tp ? totB - Q2 : Q2;
  float S3 = tp ? totB - Q3 : Q3;
  float K9  = (tid & 16) ? tot : 0.f;   // g9  (layout-A thread bit)
  float K10 = (tid & 32) ? tot : 0.f;   // g10
  float K11 = (tid & 64) ? tot : 0.f;   // g11
  float vals[21] = {tot, S0,S1,S2,S3,S4,S5,S6,S7,S8, K9,K10,K11,
                    X01,X12,X23,X34,X45,X56,X67,X78};
  #pragma unroll
  for (int i=0;i<21;i++){
    float rr = vals[i];
    for (int off=32; off; off>>=1) rr += __shfl_down(rr, off);
    vals[i] = rr;
  }
  if ((tid & 63) == 0){
    float* A = acc + b*ACCS;
    atomicAdd(A+0, vals[0]);
    #pragma unroll
    for (int p=0;p<12;p++) atomicAdd(A+1+p, vals[1+p]);
    if (t&1) atomicAdd(A+13, vals[0]);
    if (t&2) atomicAdd(A+14, vals[0]);
    if (t&4) atomicAdd(A+15, vals[0]);
    float zz = vals[0] - 2.f*vals[1];
    if (t&8) zz = -zz;
    atomicAdd(A+16, zz);
    #pragma unroll
    for (int j=0;j<8;j++) atomicAdd(A+17+j, vals[13+j]);
  }
}

// Tail: unchanged from round 2 (verified).
__global__ __launch_bounds__(256) void qr_tail(const float* __restrict__ acc, const float* __restrict__ tryv,
    const float* __restrict__ w1, const float* __restrict__ b1,
    const float* __restrict__ w2, const float* __restrict__ b2,
    const float* __restrict__ g1, const float* __restrict__ be1,
    const float* __restrict__ g2, const float* __restrict__ be2,
    const float* __restrict__ wh, const float* __restrict__ bh,
    float* __restrict__ out){
  int b = blockIdx.x * 256 + threadIdx.x;
  if (b >= BSZQ) return;
  const float* A = acc + b*ACCS;
  float tot = A[0];
  float inv = 1.f / tot;
  float Z[16], X[16];
  Z[0] = A[16] * inv;
  Z[1] = 1.f - 2.f*A[15]*inv;
  Z[2] = 1.f - 2.f*A[14]*inv;
  Z[3] = 1.f - 2.f*A[13]*inv;
  #pragma unroll
  for (int w=4; w<15; w++) Z[w] = 1.f - 2.f*A[1 + (15-w)]*inv;
  Z[15] = 1.f - 2.f*A[1]*inv;
  #pragma unroll
  for (int w=0; w<7; w++) X[w] = A[25+w]*inv;
  #pragma unroll
  for (int w=7; w<15; w++) X[w] = A[16 + (15-w)]*inv;
  X[15] = A[32]*inv;
  float th = tryv[1];
  float ct = cosf(th), st = sinf(th);
  float M4[16];
  #pragma unroll
  for (int w=0; w<16; w++) M4[w] = ct*Z[w] - st*X[w];
  float mu = 0.f;
  #pragma unroll
  for (int w=0; w<16; w++) mu += Z[w];
  mu *= (1.f/16.f);
  float var = 0.f;
  #pragma unroll
  for (int w=0; w<16; w++){ float d = Z[w]-mu; var += d*d; }
  var *= (1.f/16.f);
  float rs = rsqrtf(var + 1e-5f);
  float xln[16];
  #pragma unroll
  for (int w=0; w<16; w++) xln[w] = (Z[w]-mu)*rs*g1[16+w] + be1[16+w];
  float h[64];
  for (int j=0;j<64;j++){
    float sacc = b1[64 + j];
    #pragma unroll
    for (int w=0; w<16; w++) sacc += M4[w] * w1[1024 + j*16 + w];
    h[j] = fmaxf(sacc, 0.f);
  }
  float y[16];
  for (int w=0; w<16; w++){
    float sacc = b2[16 + w];
    #pragma unroll
    for (int j=0;j<64;j++) sacc += h[j] * w2[1024 + w*64 + j];
    y[w] = xln[w] + sacc;
  }
  mu = 0.f;
  #pragma unroll
  for (int w=0; w<16; w++) mu += y[w];
  mu *= (1.f/16.f);
  var = 0.f;
  #pragma unroll
  for (int w=0; w<16; w++){ float d = y[w]-mu; var += d*d; }
  var *= (1.f/16.f);
  rs = rsqrtf(var + 1e-5f);
  float o = bh[0];
  #pragma unroll
  for (int w=0; w<16; w++) o += ((y[w]-mu)*rs*g2[16+w] + be2[16+w]) * wh[w];
  out[b] = o;
}

extern "C" void kernel_launch(void* const* d_in, const int* in_sizes, int n_in,
                              void* d_out, int out_size, void* d_ws, size_t ws_size,
                              hipStream_t stream) {
  const float* states = (const float*)d_in[0];
  const float* ra     = (const float*)d_in[1];
  const float* trx    = (const float*)d_in[2];
  const float* tryv   = (const float*)d_in[3];
  const float* w1     = (const float*)d_in[4];
  const float* b1     = (const float*)d_in[5];
  const float* w2     = (const float*)d_in[6];
  const float* b2     = (const float*)d_in[7];
  const float* g1     = (const float*)d_in[8];
  const float* be1    = (const float*)d_in[9];
  const float* g2     = (const float*)d_in[10];
  const float* be2    = (const float*)d_in[11];
  const float* wh     = (const float*)d_in[12];
  const float* bh     = (const float*)d_in[13];
  float* out = (float*)d_out;

  float2* psi = (float2*)d_ws;                                   // 256 MiB
  float* acc  = (float*)((char*)d_ws + (size_t)BSZQ*65536*sizeof(float2)); // 512 x 40

  dim3 g(BSZQ*16);
  qr_p1<<<g, NT, 0, stream>>>(states, ra, trx, psi, acc);
  qr_p2<<<g, NT, 0, stream>>>(psi, ra, trx);
  qr_p4<<<g, NT, 0, stream>>>(psi, trx, tryv, acc);
  qr_p5<<<g, NT, 0, stream>>>(psi, trx, tryv, acc);
  qr_tail<<<2, 256, 0, stream>>>(acc, tryv, w1, b1, w2, b2, g1, be1, g2, be2, wh, bh, out);
}

// Round 4
// 806.278 us; speedup vs baseline: 1.5591x; 1.0839x over previous
//
#include <hip/hip_runtime.h>
#include <math.h>

// 16-qubit statevector, 512 batch, float2[512][65536] in d_ws (256 MiB).
// Bit convention: wire w <-> bit (15-w). 4 state passes + tail.
// NT=256, 16 amps/thread (4 reg bits). Gate/measurement algebra identical to
// round-3 (verified, absmax 0.0078): chain0 folded as T (addr = y ^ (y>>1)),
// K=C(w15->w0) as lane-shuffle CNOT, chain1 low part + K1 folded into P5
// measurement (sigma scheme). Per-stage LDS swizzles proven conflict-minimal
// for both write and read loops. P4 global gather = per-thread contiguous
// 16-amp runs (8x float4) + compile-time Gray-parity register permute.

#define NT 256
#define ACCS 40
#define BSZQ 512

struct C2 { float r, i; };
struct G1Q { C2 a, b, c, d; };

__device__ __forceinline__ C2 cmul(C2 x, C2 y){ return C2{ x.r*y.r - x.i*y.i, x.r*y.i + x.i*y.r }; }
__device__ __forceinline__ C2 cadd(C2 x, C2 y){ return C2{ x.r + y.r, x.i + y.i }; }
__device__ __forceinline__ G1Q mkRX(float th){
  float cc = cosf(0.5f*th), ss = sinf(0.5f*th);
  return G1Q{ C2{cc,0.f}, C2{0.f,-ss}, C2{0.f,-ss}, C2{cc,0.f} };
}
__device__ __forceinline__ G1Q mkRY(float th){
  float cc = cosf(0.5f*th), ss = sinf(0.5f*th);
  return G1Q{ C2{cc,0.f}, C2{-ss,0.f}, C2{ss,0.f}, C2{cc,0.f} };
}
__device__ __forceinline__ G1Q gmul(G1Q A, G1Q B){ // A*B, B applied first
  return G1Q{ cadd(cmul(A.a,B.a), cmul(A.b,B.c)),
              cadd(cmul(A.a,B.b), cmul(A.b,B.d)),
              cadd(cmul(A.c,B.a), cmul(A.d,B.c)),
              cadd(cmul(A.c,B.b), cmul(A.d,B.d)) };
}

// LDS swizzles: low4 ^= l4..7 (A) or l8..11 (B); chosen per stage so both the
// write loop and the read loop vary low4 across their fast lane bits.
__device__ __forceinline__ int swzA(int l){ return (l & 0xFF0) | (((l>>4) ^ l) & 15); }
__device__ __forceinline__ int swzB(int l){ return (l & 0xFF0) | (((l>>8) ^ l) & 15); }

__device__ __forceinline__ void greg16(float2* v, const G1Q g, const int q){
  const int bq = 1<<q;
  #pragma unroll
  for (int r=0;r<16;r++){
    if (r & bq) continue;
    float2 a0 = v[r], a1 = v[r|bq];
    v[r].x    = g.a.r*a0.x - g.a.i*a0.y + g.b.r*a1.x - g.b.i*a1.y;
    v[r].y    = g.a.r*a0.y + g.a.i*a0.x + g.b.r*a1.y + g.b.i*a1.x;
    v[r|bq].x = g.c.r*a0.x - g.c.i*a0.y + g.d.r*a1.x - g.d.i*a1.y;
    v[r|bq].y = g.c.r*a0.y + g.c.i*a0.x + g.d.r*a1.y + g.d.i*a1.x;
  }
}
__device__ __forceinline__ void creg16(float2* v, const int qc, const int qt){
  #pragma unroll
  for (int r=0;r<16;r++){
    if ((r & (1<<qc)) && !(r & (1<<qt))){
      float2 tmp = v[r]; v[r] = v[r|(1<<qt)]; v[r|(1<<qt)] = tmp;
    }
  }
}
__device__ __forceinline__ float xdot16(const float2* v, const int m){
  float s = 0.f;
  #pragma unroll
  for (int r=0;r<16;r++) s += v[r].x*v[r^m].x + v[r].y*v[r^m].y;
  return s;
}

// ---------------- P1 (L tile): input->complex, random-layer L gates + RX0 ----------------
__global__ __launch_bounds__(NT) void qs_p1(const float* __restrict__ x, const float* __restrict__ ra,
                                            const float* __restrict__ trx, float2* __restrict__ psi,
                                            float* __restrict__ acc){
  __shared__ __align__(16) float2 s[4096];
  int b = blockIdx.x >> 4, t = blockIdx.x & 15;
  int tid = threadIdx.x;
  if (t == 0 && tid < ACCS) acc[b*ACCS + tid] = 0.f;
  float trx0 = trx[0];
  G1Q RX0 = mkRX(trx0);
  float2 v[16];
  // phase alpha: regs = bits 0..3, threads = bits 4..11
  const float4* xb = (const float4*)(x + (size_t)b*65536 + t*4096 + tid*16);
  #pragma unroll
  for (int q=0;q<4;q++){
    float4 f = xb[q];
    v[4*q+0] = make_float2(f.x, 0.f);
    v[4*q+1] = make_float2(f.y, 0.f);
    v[4*q+2] = make_float2(f.z, 0.f);
    v[4*q+3] = make_float2(f.w, 0.f);
  }
  greg16(v, gmul(RX0, gmul(mkRY(ra[19]), mkRX(ra[3]))), 0);  // w15
  greg16(v, mkRX(trx0 + ra[6]),  1);                         // w14
  greg16(v, mkRX(trx0 + ra[9]),  2);                         // w13
  greg16(v, mkRX(trx0 + ra[12]), 3);                         // w12
  #pragma unroll
  for (int j=0;j<16;j++) s[swzA(j | (tid<<4))] = v[j];
  __syncthreads();
  // phase beta: regs = bits 4..7; tid: b0..3 = bits 0..3, b4..7 = bits 8..11
  #pragma unroll
  for (int r=0;r<16;r++) v[r] = s[swzA((tid&15) | (r<<4) | ((tid>>4)<<8))];
  creg16(v, 1, 0);                       // C(w10->w11)
  creg16(v, 2, 1);                       // C(w9->w10)
  creg16(v, 3, 2);                       // C(w8->w9)
  {                                      // C(w7->w8): ctrl bit8 = tid bit4, tgt bit7 = r3
    bool c8 = (tid & 16);
    #pragma unroll
    for (int r=0;r<8;r++){
      float2 lo = v[r], hi = v[r|8];
      v[r]   = c8 ? hi : lo;
      v[r|8] = c8 ? lo : hi;
    }
  }
  greg16(v, mkRX(trx0 + ra[15]), 0);     // w11
  greg16(v, mkRX(trx0 + ra[18]), 1);     // w10
  greg16(v, RX0, 2);                     // w9
  greg16(v, RX0, 3);                     // w8
  float2* pbL = psi + (size_t)b*65536 + t*4096;
  #pragma unroll
  for (int r=0;r<16;r++) pbL[(tid&15) | (r<<4) | ((tid>>4)<<8)] = v[r];
}

// ---------------- P2 (H tile): random-layer H gates + RX0 on wires 0..7 ----------------
__global__ __launch_bounds__(NT) void qs_p2(float2* __restrict__ psi, const float* __restrict__ ra,
                                            const float* __restrict__ trx){
  __shared__ __align__(16) float2 s[4096];
  int b = blockIdx.x >> 4, t = blockIdx.x & 15;
  int tid = threadIdx.x;
  float trx0 = trx[0];
  G1Q RX0 = mkRX(trx0);
  float2 v[16];
  float2* pb = psi + (size_t)b*65536;
  // phase A: regs = g8..11; tid: b0..3 = g0..3, b4..7 = g12..15
  #pragma unroll
  for (int r=0;r<16;r++)
    v[r] = pb[(tid&15) | (t<<4) | (r<<8) | ((tid>>4)<<12)];
  greg16(v, gmul(RX0, mkRY(ra[4])), 3);   // w4
  greg16(v, mkRY(ra[1]), 2);              // w5 (RY part)
  creg16(v, 1, 0);                        // C(w6->w7)
  creg16(v, 2, 1);                        // C(w5->w6)
  greg16(v, RX0, 2);                      // w5
  greg16(v, RX0, 1);                      // w6
  greg16(v, RX0, 0);                      // w7
  #pragma unroll
  for (int r=0;r<16;r++) s[swzA((tid&15) | (r<<4) | ((tid>>4)<<8))] = v[r];
  __syncthreads();
  // phase B: regs = g12..15; tid: b0..3 = g0..3, b4..7 = g8..11
  #pragma unroll
  for (int r=0;r<16;r++) v[r] = s[swzA((tid&15) | ((tid>>4)<<4) | (r<<8))];
  greg16(v, gmul(RX0, mkRY(ra[7])), 0);                     // w3
  greg16(v, gmul(RX0, mkRY(ra[10])), 1);                    // w2
  greg16(v, gmul(RX0, mkRY(ra[13])), 2);                    // w1
  greg16(v, gmul(RX0, gmul(mkRY(ra[16]), mkRX(ra[0]))), 3); // w0
  #pragma unroll
  for (int r=0;r<16;r++)
    pb[(tid&15) | (t<<4) | ((tid>>4)<<8) | (r<<12)] = v[r];
}

// ---------------- P4 (H tile on y-frame, T folded into load/store addr) ----------------
// Phases A (y0..3) -> C (y12..15) -> B (y8..11). K as lane-shuffle CNOT in A.
__global__ __launch_bounds__(NT) void qs_p4(float2* __restrict__ psi, const float* __restrict__ trx,
                                            const float* __restrict__ tryv, float* __restrict__ acc){
  __shared__ __align__(16) float2 s[4096];
  int b = blockIdx.x >> 4, t = blockIdx.x & 15;
  int tid = threadIdx.x;
  G1Q U = gmul(mkRX(trx[1]), mkRY(tryv[0]));
  float2* pb = psi + (size_t)b*65536;
  float2 v[16];
  // ---- phase A: regs y0..3; tid: b0..3 = y12..15, b4..7 = y8..11 ----
  {
    int Y = (tid>>4) | ((tid&15)<<4);          // y8..15
    int XH = Y ^ (Y>>1);                       // x8..15
    int x7 = ((t>>3) ^ Y) & 1;                 // t3 ^ y8
    int runbase = (XH<<8) | (x7<<7) | (((t ^ (t>>1)) & 7) << 4);
    const float4* rp = (const float4*)(pb + runbase);
    float2 tmp[16];
    #pragma unroll
    for (int q=0;q<8;q++){
      float4 f = rp[q];
      tmp[2*q]   = make_float2(f.x, f.y);
      tmp[2*q+1] = make_float2(f.z, f.w);
    }
    // v[j] = tmp[alpha], j bitk = parity(alpha>>k) (^15 if t0)
    if (t & 1){
      v[15]=tmp[0];  v[14]=tmp[1];  v[12]=tmp[2];  v[13]=tmp[3];
      v[ 8]=tmp[4];  v[ 9]=tmp[5];  v[11]=tmp[6];  v[10]=tmp[7];
      v[ 0]=tmp[8];  v[ 1]=tmp[9];  v[ 3]=tmp[10]; v[ 2]=tmp[11];
      v[ 7]=tmp[12]; v[ 6]=tmp[13]; v[ 4]=tmp[14]; v[ 5]=tmp[15];
    } else {
      v[ 0]=tmp[0];  v[ 1]=tmp[1];  v[ 3]=tmp[2];  v[ 2]=tmp[3];
      v[ 7]=tmp[4];  v[ 6]=tmp[5];  v[ 4]=tmp[6];  v[ 5]=tmp[7];
      v[15]=tmp[8];  v[14]=tmp[9];  v[12]=tmp[10]; v[13]=tmp[11];
      v[ 8]=tmp[12]; v[ 9]=tmp[13]; v[11]=tmp[14]; v[10]=tmp[15];
    }
    // K = C(w15->w0): ctrl y0 (reg bit0), tgt y15 (lane bit3) -> shuffle swap
    #pragma unroll
    for (int r=1;r<16;r+=2){
      v[r].x = __shfl_xor(v[r].x, 8);
      v[r].y = __shfl_xor(v[r].y, 8);
    }
    greg16(v, U, 0); greg16(v, U, 1); greg16(v, U, 2); greg16(v, U, 3); // w15,w14,w13,w12
    #pragma unroll
    for (int j=0;j<16;j++)
      s[swzB(j | ((tid>>4)<<4) | ((tid&15)<<8))] = v[j];
  }
  __syncthreads();
  float Xa, Xb, Xc, Xd;
  // ---- phase C: regs y12..15; tid: b0..3 = y0..3, b4..7 = y8..11 ----
  {
    #pragma unroll
    for (int r=0;r<16;r++)
      v[r] = s[swzB((tid&15) | ((tid>>4)<<4) | (r<<8))];
    greg16(v, U, 0); greg16(v, U, 1); greg16(v, U, 2); greg16(v, U, 3); // w3,w2,w1,w0
    creg16(v, 3, 2);  // chain1 C(w0->w1)
    creg16(v, 2, 1);  // C(w1->w2)
    creg16(v, 1, 0);  // C(w2->w3)
    Xa = xdot16(v, 8);   // X_w0 (y15)
    Xb = xdot16(v, 4);   // X_w1 (y14)
    Xc = xdot16(v, 2);   // X_w2 (y13)
    Xd = 0.f;            // <X_w0 X_w15> = y15 (reg) x y0 (lane bit0)
    #pragma unroll
    for (int r=0;r<16;r++)
      Xd += v[r].x * __shfl_xor(v[r^8].x, 1) + v[r].y * __shfl_xor(v[r^8].y, 1);
    __syncthreads();
    #pragma unroll
    for (int r=0;r<16;r++)
      s[swzB((tid&15) | ((tid>>4)<<4) | (r<<8))] = v[r];
  }
  __syncthreads();
  // ---- phase B: regs y8..11; tid: b0..3 = y0..3, b4..7 = y12..15 ----
  float Xe, Xf, Xg, Xh;
  {
    #pragma unroll
    for (int r=0;r<16;r++)
      v[r] = s[swzB((tid&15) | (r<<4) | ((tid>>4)<<8))];
    greg16(v, U, 0); greg16(v, U, 1); greg16(v, U, 2); greg16(v, U, 3); // w7,w6,w5,w4
    {                                  // C(w3->w4): ctrl y12 = tid bit4, tgt y11 = r3
      bool c12 = (tid & 16);
      #pragma unroll
      for (int r=0;r<8;r++){
        float2 lo = v[r], hi = v[r|8];
        v[r]   = c12 ? hi : lo;
        v[r|8] = c12 ? lo : hi;
      }
    }
    creg16(v, 3, 2);  // C(w4->w5)
    creg16(v, 2, 1);  // C(w5->w6)
    creg16(v, 1, 0);  // C(w6->w7)
    Xe = 0.f;         // X_w3 (y12 = lane bit4)
    #pragma unroll
    for (int r=0;r<16;r++)
      Xe += v[r].x * __shfl_xor(v[r].x, 16) + v[r].y * __shfl_xor(v[r].y, 16);
    Xf = xdot16(v, 8);   // X_w4
    Xg = xdot16(v, 4);   // X_w5
    Xh = xdot16(v, 2);   // X_w6
    #pragma unroll
    for (int r=0;r<16;r++){
      int yg = (tid&15) | (t<<4) | (r<<8) | ((tid>>4)<<12);
      pb[yg ^ (yg>>1)] = v[r];
    }
  }
  float vals[8] = {Xa, Xb, Xc, Xe, Xf, Xg, Xh, Xd};
  #pragma unroll
  for (int i=0;i<8;i++){
    float rr = vals[i];
    for (int off=32; off; off>>=1) rr += __shfl_down(rr, off);
    vals[i] = rr;
  }
  if ((tid & 63) == 0){
    float* A = acc + b*ACCS;
    #pragma unroll
    for (int i=0;i<7;i++) atomicAdd(A+25+i, vals[i]);
    atomicAdd(A+32, vals[7]);
  }
}

// ---------------- P5 (L tile, read-only, T un-fold gather): U w8..11 + measures ----------------
__global__ __launch_bounds__(NT) void qs_p5(const float2* __restrict__ psi, const float* __restrict__ trx,
                                            const float* __restrict__ tryv, float* __restrict__ acc){
  __shared__ __align__(16) float2 s[4096];
  int b = blockIdx.x >> 4, t = blockIdx.x & 15;
  int tid = threadIdx.x;
  G1Q U = gmul(mkRX(trx[1]), mkRY(tryv[0]));
  const float2* pb = psi + (size_t)b*65536;
  float2 v[16];
  // phase A: regs ul4..7; tid: b0..3 = ul0..3, b4 = ul8, b5..7 = ul9..11
  #pragma unroll
  for (int r=0;r<16;r++){
    int ul = (tid&15) | (r<<4) | ((tid>>4)<<8);
    int ug = (t<<12) | ul;
    v[r] = pb[ug ^ (ug>>1)];
  }
  greg16(v, U, 0); greg16(v, U, 1); greg16(v, U, 2); greg16(v, U, 3); // w11..w8
  float totA=0.f, S4l=0.f, S5l=0.f, S6l=0.f, S7l=0.f;
  #pragma unroll
  for (int r=0;r<16;r++){
    float a2 = v[r].x*v[r].x + v[r].y*v[r].y;
    totA += a2;
    if (__popc(r)&1)    S4l += a2;
    if (__popc(r>>1)&1) S5l += a2;
    if (__popc(r>>2)&1) S6l += a2;
    if (__popc(r>>3)&1) S7l += a2;
  }
  bool u8 = (tid & 16);
  float S4 = u8 ? totA - S4l : S4l;
  float S5 = u8 ? totA - S5l : S5l;
  float S6 = u8 ? totA - S6l : S6l;
  float S7 = u8 ? totA - S7l : S7l;
  float S8 = u8 ? totA : 0.f;
  float K9  = (tid & 32) ? totA : 0.f;
  float K10 = (tid & 64) ? totA : 0.f;
  float K11 = (tid & 128)? totA : 0.f;
  float X45 = xdot16(v,3), X56 = xdot16(v,6), X67 = xdot16(v,12);
  float X78 = 0.f;   // ul7 (reg bit3) x ul8 (lane bit4)
  #pragma unroll
  for (int r=0;r<16;r++)
    X78 += v[r].x * __shfl_xor(v[r^8].x, 16) + v[r].y * __shfl_xor(v[r^8].y, 16);
  #pragma unroll
  for (int r=0;r<16;r++) s[swzA((tid&15) | (r<<4) | ((tid>>4)<<8))] = v[r];
  __syncthreads();
  // phase B: regs ul0..3; tid: b0..3 = ul4..7, b4..7 = ul8..11
  #pragma unroll
  for (int r=0;r<16;r++) v[r] = s[swzA(r | ((tid&15)<<4) | ((tid>>4)<<8))];
  float totB=0.f, Q0=0.f, Q1=0.f, Q2=0.f, Q3=0.f;
  #pragma unroll
  for (int r=0;r<16;r++){
    float a2 = v[r].x*v[r].x + v[r].y*v[r].y;
    totB += a2;
    if (__popc(r)&1)    Q0 += a2;
    if (__popc(r>>1)&1) Q1 += a2;
    if (__popc(r>>2)&1) Q2 += a2;
    if (__popc(r>>3)&1) Q3 += a2;
  }
  int tp = __popc(tid & 31) & 1;   // parity(ul4..ul8)
  float S0 = tp ? totB - Q0 : Q0;
  float S1 = tp ? totB - Q1 : Q1;
  float S2 = tp ? totB - Q2 : Q2;
  float S3 = tp ? totB - Q3 : Q3;
  float X01 = xdot16(v,3), X12 = xdot16(v,6), X23 = xdot16(v,12);
  float X34 = 0.f;   // ul3 (reg bit3) x ul4 (lane bit0)
  #pragma unroll
  for (int r=0;r<16;r++)
    X34 += v[r].x * __shfl_xor(v[r^8].x, 1) + v[r].y * __shfl_xor(v[r^8].y, 1);
  float vals[21] = {totA, S0,S1,S2,S3,S4,S5,S6,S7,S8, K9,K10,K11,
                    X01,X12,X23,X34,X45,X56,X67,X78};
  #pragma unroll
  for (int i=0;i<21;i++){
    float rr = vals[i];
    for (int off=32; off; off>>=1) rr += __shfl_down(rr, off);
    vals[i] = rr;
  }
  if ((tid & 63) == 0){
    float* A = acc + b*ACCS;
    atomicAdd(A+0, vals[0]);
    #pragma unroll
    for (int p=0;p<12;p++) atomicAdd(A+1+p, vals[1+p]);
    if (t&1) atomicAdd(A+13, vals[0]);
    if (t&2) atomicAdd(A+14, vals[0]);
    if (t&4) atomicAdd(A+15, vals[0]);
    float zz = vals[0] - 2.f*vals[1];
    if (t&8) zz = -zz;
    atomicAdd(A+16, zz);
    #pragma unroll
    for (int j=0;j<8;j++) atomicAdd(A+17+j, vals[13+j]);
  }
}

// ---------------- Tail (unchanged, verified) ----------------
__global__ __launch_bounds__(256) void qs_tail(const float* __restrict__ acc, const float* __restrict__ tryv,
    const float* __restrict__ w1, const float* __restrict__ b1,
    const float* __restrict__ w2, const float* __restrict__ b2,
    const float* __restrict__ g1, const float* __restrict__ be1,
    const float* __restrict__ g2, const float* __restrict__ be2,
    const float* __restrict__ wh, const float* __restrict__ bh,
    float* __restrict__ out){
  int b = blockIdx.x * 256 + threadIdx.x;
  if (b >= BSZQ) return;
  const float* A = acc + b*ACCS;
  float tot = A[0];
  float inv = 1.f / tot;
  float Z[16], X[16];
  Z[0] = A[16] * inv;
  Z[1] = 1.f - 2.f*A[15]*inv;
  Z[2] = 1.f - 2.f*A[14]*inv;
  Z[3] = 1.f - 2.f*A[13]*inv;
  #pragma unroll
  for (int w=4; w<15; w++) Z[w] = 1.f - 2.f*A[1 + (15-w)]*inv;
  Z[15] = 1.f - 2.f*A[1]*inv;
  #pragma unroll
  for (int w=0; w<7; w++) X[w] = A[25+w]*inv;
  #pragma unroll
  for (int w=7; w<15; w++) X[w] = A[16 + (15-w)]*inv;
  X[15] = A[32]*inv;
  float th = tryv[1];
  float ct = cosf(th), st = sinf(th);
  float M4[16];
  #pragma unroll
  for (int w=0; w<16; w++) M4[w] = ct*Z[w] - st*X[w];
  float mu = 0.f;
  #pragma unroll
  for (int w=0; w<16; w++) mu += Z[w];
  mu *= (1.f/16.f);
  float var = 0.f;
  #pragma unroll
  for (int w=0; w<16; w++){ float d = Z[w]-mu; var += d*d; }
  var *= (1.f/16.f);
  float rs = rsqrtf(var + 1e-5f);
  float xln[16];
  #pragma unroll
  for (int w=0; w<16; w++) xln[w] = (Z[w]-mu)*rs*g1[16+w] + be1[16+w];
  float h[64];
  for (int j=0;j<64;j++){
    float sacc = b1[64 + j];
    #pragma unroll
    for (int w=0; w<16; w++) sacc += M4[w] * w1[1024 + j*16 + w];
    h[j] = fmaxf(sacc, 0.f);
  }
  float y[16];
  for (int w=0; w<16; w++){
    float sacc = b2[16 + w];
    #pragma unroll
    for (int j=0;j<64;j++) sacc += h[j] * w2[1024 + w*64 + j];
    y[w] = xln[w] + sacc;
  }
  mu = 0.f;
  #pragma unroll
  for (int w=0; w<16; w++) mu += y[w];
  mu *= (1.f/16.f);
  var = 0.f;
  #pragma unroll
  for (int w=0; w<16; w++){ float d = y[w]-mu; var += d*d; }
  var *= (1.f/16.f);
  rs = rsqrtf(var + 1e-5f);
  float o = bh[0];
  #pragma unroll
  for (int w=0; w<16; w++) o += ((y[w]-mu)*rs*g2[16+w] + be2[16+w]) * wh[w];
  out[b] = o;
}

extern "C" void kernel_launch(void* const* d_in, const int* in_sizes, int n_in,
                              void* d_out, int out_size, void* d_ws, size_t ws_size,
                              hipStream_t stream) {
  const float* states = (const float*)d_in[0];
  const float* ra     = (const float*)d_in[1];
  const float* trx    = (const float*)d_in[2];
  const float* tryv   = (const float*)d_in[3];
  const float* w1     = (const float*)d_in[4];
  const float* b1     = (const float*)d_in[5];
  const float* w2     = (const float*)d_in[6];
  const float* b2     = (const float*)d_in[7];
  const float* g1     = (const float*)d_in[8];
  const float* be1    = (const float*)d_in[9];
  const float* g2     = (const float*)d_in[10];
  const float* be2    = (const float*)d_in[11];
  const float* wh     = (const float*)d_in[12];
  const float* bh     = (const float*)d_in[13];
  float* out = (float*)d_out;

  float2* psi = (float2*)d_ws;                                             // 256 MiB
  float* acc  = (float*)((char*)d_ws + (size_t)BSZQ*65536*sizeof(float2)); // 512 x 40

  dim3 g(BSZQ*16);
  qs_p1<<<g, NT, 0, stream>>>(states, ra, trx, psi, acc);
  qs_p2<<<g, NT, 0, stream>>>(psi, ra, trx);
  qs_p4<<<g, NT, 0, stream>>>(psi, trx, tryv, acc);
  qs_p5<<<g, NT, 0, stream>>>(psi, trx, tryv, acc);
  qs_tail<<<2, 256, 0, stream>>>(acc, tryv, w1, b1, w2, b2, g1, be1, g2, be2, wh, bh, out);
}